// Round 9
// baseline (226.104 us; speedup 1.0000x reference)
//
#include <hip/hip_runtime.h>
#include <hip/hip_bf16.h>

#define H_ 96
#define W_ 96
#define HW_ 9216
#define C_ 256
#define KO_ 27
#define EPS_ 1e-5f

typedef unsigned short u16;
typedef unsigned short ushort8 __attribute__((ext_vector_type(8)));
typedef unsigned short ushort4v __attribute__((ext_vector_type(4)));
typedef short short8v __attribute__((ext_vector_type(8)));
typedef float float4v __attribute__((ext_vector_type(4)));

__device__ __forceinline__ float b2f(u16 u) {
    return __uint_as_float(((unsigned int)u) << 16);
}
__device__ __forceinline__ u16 f2b(float f) {
    __hip_bfloat16 h = __float2bfloat16(f);
    union { __hip_bfloat16 h; u16 u; } cv; cv.h = h; return cv.u;
}
__device__ __forceinline__ unsigned int pack2(float a, float b) {
    union { __hip_bfloat162 h; unsigned int u; } cv;
    cv.h = __float22bfloat162_rn(make_float2(a, b));
    return cv.u;
}
// async global->LDS, 16B per lane; LDS dest = uniform base + lane*16
__device__ __forceinline__ void glds16(const u16* g, u16* l) {
    __builtin_amdgcn_global_load_lds(
        (const __attribute__((address_space(1))) void*)g,
        (__attribute__((address_space(3))) void*)l, 16, 0, 0);
}

// ---------------- kernel 1: prep (R7-proven) -------------------------------
__global__ __launch_bounds__(256) void prep_kernel(
    const float* __restrict__ x,
    const float* __restrict__ w_conv, const float* __restrict__ w_off,
    const float* __restrict__ b_conv,
    const float* __restrict__ gamma, const float* __restrict__ beta,
    const float* __restrict__ rmean, const float* __restrict__ rvar,
    float* __restrict__ AB, u16* __restrict__ WQ, u16* __restrict__ WO,
    u16* __restrict__ XT)
{
    __shared__ u16 sbuf[3200];
    const int bx = blockIdx.x;
    const int tid = threadIdx.x;

    if (bx < 384) {
        u16 (*ls)[100] = (u16 (*)[100])sbuf;
        int h    = bx % 96;
        int t2   = bx / 96;
        int b    = t2 >> 1;
        int half = t2 & 1;
        for (int cgi = 0; cgi < 4; ++cgi) {
            int c0 = (half * 4 + cgi) * 32;
            for (int e = tid; e < 32 * W_; e += 256) {
                int ci = e / W_, w = e % W_;
                ls[ci][w] = f2b(x[((b * C_ + c0 + ci) * H_ + h) * W_ + w]);
            }
            __syncthreads();
            for (int u = tid; u < 768; u += 256) {
                int g4 = u & 7, w = u >> 3;
                ushort4v v;
#pragma unroll
                for (int t = 0; t < 4; t++) v[t] = ls[g4 * 4 + t][w];
                *(ushort4v*)&XT[((b * H_ + h) * W_ + w) * C_ + c0 + g4 * 4] = v;
            }
            __syncthreads();
        }
    } else if (bx < 640) {
        int o = bx - 384;
        for (int i = tid; i < 2304; i += 256)
            sbuf[i] = f2b(w_conv[o * 2304 + i]);
        __syncthreads();
        int cg = tid >> 5, ln = tid & 31;
#pragma unroll
        for (int k = 0; k < 9; ++k)
            WQ[(k * 8 + cg) * 8192 + o * 32 + ln] = sbuf[(cg * 32 + ln) * 9 + k];
    } else if (bx < 672) {
        int o = bx - 640;
        for (int i = tid; i < 2304; i += 256)
            sbuf[i] = (o < KO_) ? f2b(w_off[o * 2304 + i]) : (u16)0;
        __syncthreads();
        int cg = tid >> 5, ln = tid & 31;
#pragma unroll
        for (int k = 0; k < 9; ++k)
            WO[(k * 8 + cg) * 1024 + o * 32 + ln] = sbuf[(cg * 32 + ln) * 9 + k];
    } else {
        int o = tid;
        float sc = gamma[o] * rsqrtf(rvar[o] + EPS_);
        AB[o] = sc;
        AB[256 + o] = beta[o] + (b_conv[o] - rmean[o]) * sc;
    }
}

// ---------------- kernel 2: offsets GEMM -> OFF (R7-proven) ----------------
__global__ __launch_bounds__(256) void offsets_kernel(
    const u16* __restrict__ XT, const u16* __restrict__ WO,
    const float* __restrict__ b_off, float* __restrict__ OFF)
{
    __shared__ float red[4][2][32][17];

    const int tid  = threadIdx.x;
    const int wave = tid >> 6;
    const int lane = tid & 63;
    const int quad = lane >> 4;
    const int l15  = lane & 15;

    const int n0 = blockIdx.x * 32;
    const int b  = n0 / HW_;
    const int p0 = n0 - b * HW_;
    const int h  = p0 / W_;
    const int w0 = p0 % W_;

    float4v oa[2][2];
#pragma unroll
    for (int ph = 0; ph < 2; ph++)
#pragma unroll
        for (int hh = 0; hh < 2; hh++)
            oa[ph][hh] = float4v{0.f, 0.f, 0.f, 0.f};

    int basec0 = 0, basec1 = 0; bool vld0 = true, vld1 = true;
    auto oset = [&](int tap) {
        int py = h + tap / 3 - 1;
        bool vy = (unsigned)py < (unsigned)H_;
        int pyc = min(max(py, 0), H_ - 1);
        int rowb = (b * H_ + pyc) * W_;
        {
            int pxl = w0 + l15 + tap % 3 - 1;
            vld0 = vy && ((unsigned)pxl < (unsigned)W_);
            basec0 = (rowb + min(max(pxl, 0), W_ - 1)) * C_ + quad * 8;
        }
        {
            int pxl = w0 + 16 + l15 + tap % 3 - 1;
            vld1 = vy && ((unsigned)pxl < (unsigned)W_);
            basec1 = (rowb + min(max(pxl, 0), W_ - 1)) * C_ + quad * 8;
        }
    };
    auto bld0 = [&](int c32) -> ushort8 {
        ushort8 v = *(const ushort8*)(XT + basec0 + (c32 & 7) * 32);
#pragma unroll
        for (int j = 0; j < 8; j++) v[j] = vld0 ? v[j] : (u16)0;
        return v;
    };
    auto bld1 = [&](int c32) -> ushort8 {
        ushort8 v = *(const ushort8*)(XT + basec1 + (c32 & 7) * 32);
#pragma unroll
        for (int j = 0; j < 8; j++) v[j] = vld1 ? v[j] : (u16)0;
        return v;
    };
    const int i0 = wave * 18, i1 = i0 + 18;
    int curtap = i0 >> 3;
    oset(curtap);
    ushort8 b0 = bld0(i0), b1 = bld1(i0);
    short8v wa = *(const short8v*)(WO + i0 * 1024 + l15 * 32 + quad * 8);
    short8v wb = *(const short8v*)(WO + i0 * 1024 + l15 * 32 + quad * 8 + 512);
    for (int i = i0; i < i1; ++i) {
        ushort8 c0v = b0, c1v = b1;
        short8v wac = wa, wbc = wb;
        int nx = i + 1;
        if (nx < i1) {
            int t = nx >> 3;
            if (t != curtap) { oset(t); curtap = t; }
            b0 = bld0(nx); b1 = bld1(nx);
            wa = *(const short8v*)(WO + nx * 1024 + l15 * 32 + quad * 8);
            wb = *(const short8v*)(WO + nx * 1024 + l15 * 32 + quad * 8 + 512);
        }
        union { ushort8 u; short8v s; } u0, u1; u0.u = c0v; u1.u = c1v;
        oa[0][0] = __builtin_amdgcn_mfma_f32_16x16x32_bf16(wac, u0.s, oa[0][0], 0, 0, 0);
        oa[0][1] = __builtin_amdgcn_mfma_f32_16x16x32_bf16(wbc, u0.s, oa[0][1], 0, 0, 0);
        oa[1][0] = __builtin_amdgcn_mfma_f32_16x16x32_bf16(wac, u1.s, oa[1][0], 0, 0, 0);
        oa[1][1] = __builtin_amdgcn_mfma_f32_16x16x32_bf16(wbc, u1.s, oa[1][1], 0, 0, 0);
    }
#pragma unroll
    for (int r = 0; r < 4; ++r) {
        red[wave][0][quad * 4 + r][l15]      = oa[0][0][r];
        red[wave][0][16 + quad * 4 + r][l15] = oa[0][1][r];
        red[wave][1][quad * 4 + r][l15]      = oa[1][0][r];
        red[wave][1][16 + quad * 4 + r][l15] = oa[1][1][r];
    }
    __syncthreads();
    for (int u = tid; u < 1024; u += 256) {
        int px = u & 31, o = u >> 5;
        if (o < KO_) {
            int ph = px >> 4, pp = px & 15;
            float v = red[0][ph][o][pp] + red[1][ph][o][pp]
                    + red[2][ph][o][pp] + red[3][ph][o][pp] + b_off[o];
            OFF[(size_t)(n0 + px) * 32 + o] =
                (o < 18) ? v : 1.f / (1.f + expf(-v));
        }
    }
}

// ---------------- kernel 3: FUSED gather+lerp+GEMM+BN+relu+residual --------
// 288 blocks x 512 threads. Tile = 256o x 64px (64 contiguous n; rows may be
// crossed, handled per-thread). 8 waves = 64o x 32px each. A (32KB) staged
// once per chunk via glds16, SHARED by all 64 px -> WQ L2 re-read halved vs
// the 576x32 config. R3-proven 2-barrier chunk loop.
__global__ __launch_bounds__(512) void fused_kernel(
    const float* __restrict__ x, const u16* __restrict__ XT,
    const float* __restrict__ OFF, const u16* __restrict__ WQ,
    const float* __restrict__ AB, float* __restrict__ out)
{
    __shared__ __align__(16) u16 sA[16384];   // 32 KB [cc2][o256][cp32]
    __shared__ __align__(16) u16 sB[4096];    //  8 KB [cc2][px64][cp32]
    __shared__ float offv[64][36];            //  9 KB (stride 36: 16B-aligned
                                              //  rows, conflict-spread reads)

    const int tid  = threadIdx.x;
    const int wave = tid >> 6;                // 0..7
    const int lane = tid & 63;
    const int quad = lane >> 4;
    const int l15  = lane & 15;

    // 288 = 8 * 36 -> bijective XCD swizzle
    const int bid = blockIdx.x;
    const int swz = (bid & 7) * 36 + (bid >> 3);
    const int n0  = swz * 64;
    const int b   = n0 / HW_;                 // 64 | 9216: no batch straddle
    const int p0  = n0 - b * HW_;

    const int wo = (wave & 3) * 64;           // wave o-slice
    const int wp = (wave >> 2) * 32;          // wave px-half

    // producer identity: one (px, ch-octet) unit per thread
    const int pj    = tid & 7;                // ch-octet 0..7
    const int ptile = ((tid >> 3) & 31) | ((tid >> 8) << 5);   // 0..63
    const int pixt  = p0 + ptile;
    const int hp    = pixt / W_;
    const int wpx   = pixt % W_;
    const int sboff = (pj >> 2) * 2048 + ptile * 32 + (pj & 3) * 8;

    // load OFF tile (64 px x 32 f32) -> offv
    {
        int i = tid >> 3, j4 = (tid & 7) * 4;
        float4 v = *(const float4*)(OFF + (size_t)(n0 + i) * 32 + j4);
        *(float4*)&offv[i][j4] = v;
    }
    __syncthreads();

    float4v acc[4][2];
#pragma unroll
    for (int i = 0; i < 4; i++)
#pragma unroll
        for (int jj = 0; jj < 2; jj++)
            acc[i][jj] = float4v{0.f, 0.f, 0.f, 0.f};

    const int le8 = lane * 8;

    float fc0, fc1, fc2, fc3, fn0, fn1, fn2, fn3;
    int a00, a01, a10, a11;

    auto tap_setup = [&](int tap) {
        float dy = offv[ptile][2 * tap];
        float dx = offv[ptile][2 * tap + 1];
        float m  = offv[ptile][18 + tap];
        float py  = (float)(hp + tap / 3 - 1) + dy;
        float pxx = (float)(wpx + tap % 3 - 1) + dx;
        float y0f = floorf(py), x0f = floorf(pxx);
        float ly = py - y0f, lx = pxx - x0f;
        int y0 = (int)y0f, x0i = (int)x0f;
        int y1 = y0 + 1, x1 = x0i + 1;
        bool vy0 = (unsigned)y0 < (unsigned)H_;
        bool vy1 = (unsigned)y1 < (unsigned)H_;
        bool vx0 = (unsigned)x0i < (unsigned)W_;
        bool vx1 = (unsigned)x1 < (unsigned)W_;
        fn0 = (vy0 && vx0) ? (1.f - ly) * (1.f - lx) * m : 0.f;
        fn1 = (vy0 && vx1) ? (1.f - ly) * lx * m : 0.f;
        fn2 = (vy1 && vx0) ? ly * (1.f - lx) * m : 0.f;
        fn3 = (vy1 && vx1) ? ly * lx * m : 0.f;
        int y0c = min(max(y0, 0), H_ - 1), y1c = min(max(y1, 0), H_ - 1);
        int x0c = min(max(x0i, 0), W_ - 1), x1c = min(max(x1, 0), W_ - 1);
        a00 = ((b * H_ + y0c) * W_ + x0c) * C_;
        a01 = ((b * H_ + y0c) * W_ + x1c) * C_;
        a10 = ((b * H_ + y1c) * W_ + x0c) * C_;
        a11 = ((b * H_ + y1c) * W_ + x1c) * C_;
    };
    auto stageA = [&](int tap, int q) {
#pragma unroll
        for (int i = 0; i < 4; ++i) {
            int unit = i * 8 + wave;             // 0..31, wave-uniform
            int cc = unit >> 4;
            glds16(WQ + (size_t)(tap * 8 + q * 2 + cc) * 8192
                      + (unit & 15) * 512 + le8,
                   &sA[unit * 512]);
        }
    };

    // ---- prologue: tap 0, chunk 0 gathers + A-stage ----
    tap_setup(0);
    fc0 = fn0; fc1 = fn1; fc2 = fn2; fc3 = fn3;
    ushort8 gc00 = *(const ushort8*)(XT + a00 + pj * 8);
    ushort8 gc01 = *(const ushort8*)(XT + a01 + pj * 8);
    ushort8 gc10 = *(const ushort8*)(XT + a10 + pj * 8);
    ushort8 gc11 = *(const ushort8*)(XT + a11 + pj * 8);
    stageA(0, 0);
    ushort8 gn00{}, gn01{}, gn10{}, gn11{};

#pragma unroll 4
    for (int ch = 0; ch < 36; ++ch) {
        // ---- P1: lerp current gathers -> sB ----
        {
            float v[8];
#pragma unroll
            for (int t = 0; t < 8; t++)
                v[t] = fc0 * b2f(gc00[t]) + fc1 * b2f(gc01[t])
                     + fc2 * b2f(gc10[t]) + fc3 * b2f(gc11[t]);
            uint4 sv;
            sv.x = pack2(v[0], v[1]);
            sv.y = pack2(v[2], v[3]);
            sv.z = pack2(v[4], v[5]);
            sv.w = pack2(v[6], v[7]);
            *(uint4*)&sB[sboff] = sv;
        }
        asm volatile("s_waitcnt vmcnt(0) lgkmcnt(0)" ::: "memory");
        __builtin_amdgcn_s_barrier();            // sA + sB for ch ready

        // ---- P2: fragment reads ----
        short8v af[2][4], bfr[2][2];
#pragma unroll
        for (int cc = 0; cc < 2; ++cc) {
#pragma unroll
            for (int mt = 0; mt < 4; ++mt)
                af[cc][mt] = *(const short8v*)
                    &sA[cc * 8192 + (wo + mt * 16 + l15) * 32 + quad * 8];
#pragma unroll
            for (int nt = 0; nt < 2; ++nt)
                bfr[cc][nt] = *(const short8v*)
                    &sB[cc * 2048 + (wp + nt * 16 + l15) * 32 + quad * 8];
        }
        asm volatile("s_waitcnt lgkmcnt(0)" ::: "memory");
        __builtin_amdgcn_s_barrier();            // reads done; sA/sB free

        // ---- P3: prefetch chunk ch+1 (gathers + A-stage), then MFMA ----
        if (ch < 35) {
            const int chn = ch + 1, tapn = chn >> 2, qn = chn & 3;
            if (qn == 0) tap_setup(tapn);
            const int cb = qn * 64 + pj * 8;
            gn00 = *(const ushort8*)(XT + a00 + cb);
            gn01 = *(const ushort8*)(XT + a01 + cb);
            gn10 = *(const ushort8*)(XT + a10 + cb);
            gn11 = *(const ushort8*)(XT + a11 + cb);
            stageA(tapn, qn);
        }
        __builtin_amdgcn_s_setprio(1);
#pragma unroll
        for (int cc = 0; cc < 2; ++cc)
#pragma unroll
            for (int mt = 0; mt < 4; ++mt)
#pragma unroll
                for (int nt = 0; nt < 2; ++nt)
                    acc[mt][nt] = __builtin_amdgcn_mfma_f32_16x16x32_bf16(
                        af[cc][mt], bfr[cc][nt], acc[mt][nt], 0, 0, 0);
        __builtin_amdgcn_s_setprio(0);
        gc00 = gn00; gc01 = gn01; gc10 = gn10; gc11 = gn11;
        fc0 = fn0; fc1 = fn1; fc2 = fn2; fc3 = fn3;
    }

    // epilogue: BN fold + relu + residual
    const float* Ao = AB;
    const float* Bo = AB + 256;
#pragma unroll
    for (int mt = 0; mt < 4; mt++) {
#pragma unroll
        for (int nt = 0; nt < 2; nt++) {
            int pix = p0 + wp + nt * 16 + l15;
#pragma unroll
            for (int r = 0; r < 4; r++) {
                int o = wo + mt * 16 + quad * 4 + r;
                float v = acc[mt][nt][r] * Ao[o] + Bo[o];
                v = fmaxf(v, 0.f);
                int gi = (b * C_ + o) * HW_ + pix;
                out[gi] = x[gi] + v;
            }
        }
    }
}

extern "C" void kernel_launch(void* const* d_in, const int* in_sizes, int n_in,
                              void* d_out, int out_size, void* d_ws, size_t ws_size,
                              hipStream_t stream)
{
    (void)in_sizes; (void)n_in; (void)out_size; (void)ws_size;
    const float* x      = (const float*)d_in[0];
    const float* w_off  = (const float*)d_in[1];
    const float* b_off  = (const float*)d_in[2];
    const float* w_conv = (const float*)d_in[3];
    const float* b_conv = (const float*)d_in[4];
    const float* gamma  = (const float*)d_in[5];
    const float* beta   = (const float*)d_in[6];
    const float* rmean  = (const float*)d_in[7];
    const float* rvar   = (const float*)d_in[8];
    float* out = (float*)d_out;

    float* ws = (float*)d_ws;
    float* AB = ws;                            // 512 floats
    u16* WQ = (u16*)(AB + 512);                // 589824 u16
    u16* WO = WQ + 589824;                     // 73728 u16
    u16* XT = WO + 73728;                      // 4718592 u16
    float* OFF = (float*)(XT + 4718592);       // 589824 f32

    prep_kernel<<<673, 256, 0, stream>>>(x, w_conv, w_off, b_conv, gamma, beta,
                                         rmean, rvar, AB, WQ, WO, XT);
    offsets_kernel<<<576, 256, 0, stream>>>(XT, WO, b_off, OFF);
    fused_kernel<<<288, 512, 0, stream>>>(x, XT, OFF, WQ, AB, out);
}

// Round 11
// 171.902 us; speedup vs baseline: 1.3153x; 1.3153x over previous
//
#include <hip/hip_runtime.h>
#include <hip/hip_bf16.h>

#define H_ 96
#define W_ 96
#define HW_ 9216
#define C_ 256
#define KO_ 27
#define EPS_ 1e-5f

typedef unsigned short u16;
typedef unsigned short ushort8 __attribute__((ext_vector_type(8)));
typedef unsigned short ushort4v __attribute__((ext_vector_type(4)));
typedef short short8v __attribute__((ext_vector_type(8)));
typedef float float4v __attribute__((ext_vector_type(4)));

__device__ __forceinline__ float b2f(u16 u) {
    return __uint_as_float(((unsigned int)u) << 16);
}
__device__ __forceinline__ u16 f2b(float f) {
    __hip_bfloat16 h = __float2bfloat16(f);
    union { __hip_bfloat16 h; u16 u; } cv; cv.h = h; return cv.u;
}
__device__ __forceinline__ unsigned int pack2(float a, float b) {
    union { __hip_bfloat162 h; unsigned int u; } cv;
    cv.h = __float22bfloat162_rn(make_float2(a, b));
    return cv.u;
}
// async global->LDS, 16B per lane; LDS dest = uniform base + lane*16
__device__ __forceinline__ void glds16(const u16* g, u16* l) {
    __builtin_amdgcn_global_load_lds(
        (const __attribute__((address_space(1))) void*)g,
        (__attribute__((address_space(3))) void*)l, 16, 0, 0);
}

// ---------------- kernel 1: prep ------------------------------------------
// blocks 0..575:   XT transpose, unit=(b,h,seg32), float4 loads / 16B stores
// blocks 576..831: WQ repack (one o each; R7-proven)
// blocks 832..863: WO repack (one o each, o>=27 zeroed; R7-proven)
// block 864:       AB BN fold
__global__ __launch_bounds__(256) void prep_kernel(
    const float* __restrict__ x,
    const float* __restrict__ w_conv, const float* __restrict__ w_off,
    const float* __restrict__ b_conv,
    const float* __restrict__ gamma, const float* __restrict__ beta,
    const float* __restrict__ rmean, const float* __restrict__ rvar,
    float* __restrict__ AB, u16* __restrict__ WQ, u16* __restrict__ WO,
    u16* __restrict__ XT)
{
    __shared__ __align__(16) u16 sbuf[32][264];   // 16.9 KB (XT tile / w-buf)
    const int bx = blockIdx.x;
    const int tid = threadIdx.x;

    if (bx < 576) {
        // XT: ls[w][c] = x[bb][c][hh][w0s+w]; store 8-c runs per px
        const int seg = bx % 3, hh = (bx / 3) % 96, bb = bx / 288;
        const int w0s = seg * 32;
        {
            const int c = tid;
            const float* xp = x + ((bb * C_ + c) * H_ + hh) * W_ + w0s;
            float4 xv[8];
#pragma unroll
            for (int j = 0; j < 8; j++) xv[j] = *(const float4*)(xp + j * 4);
#pragma unroll
            for (int j = 0; j < 8; j++) {
                sbuf[j * 4 + 0][c] = f2b(xv[j].x);
                sbuf[j * 4 + 1][c] = f2b(xv[j].y);
                sbuf[j * 4 + 2][c] = f2b(xv[j].z);
                sbuf[j * 4 + 3][c] = f2b(xv[j].w);
            }
        }
        __syncthreads();
#pragma unroll
        for (int it = 0; it < 4; ++it) {
            int u = it * 256 + tid;
            int px = u >> 5, slot = u & 31;
            ushort8 v = *(const ushort8*)&sbuf[px][slot * 8];
            *(ushort8*)&XT[((bb * H_ + hh) * W_ + w0s + px) * C_ + slot * 8] = v;
        }
    } else if (bx < 832) {
        int o = bx - 576;
        u16* flat = &sbuf[0][0];
        for (int i = tid; i < 2304; i += 256)
            flat[i] = f2b(w_conv[o * 2304 + i]);
        __syncthreads();
        int cg = tid >> 5, ln = tid & 31;
#pragma unroll
        for (int k = 0; k < 9; ++k)
            WQ[(k * 8 + cg) * 8192 + o * 32 + ln] = flat[(cg * 32 + ln) * 9 + k];
    } else if (bx < 864) {
        int o = bx - 832;
        u16* flat = &sbuf[0][0];
        for (int i = tid; i < 2304; i += 256)
            flat[i] = (o < KO_) ? f2b(w_off[o * 2304 + i]) : (u16)0;
        __syncthreads();
        int cg = tid >> 5, ln = tid & 31;
#pragma unroll
        for (int k = 0; k < 9; ++k)
            WO[(k * 8 + cg) * 1024 + o * 32 + ln] = flat[(cg * 32 + ln) * 9 + k];
    } else {
        int o = tid;
        float sc = gamma[o] * rsqrtf(rvar[o] + EPS_);
        AB[o] = sc;
        AB[256 + o] = beta[o] + (b_conv[o] - rmean[o]) * sc;
    }
}

// ---------------- kernel 2: offsets prologue + R3-best fused loop ----------
// 576 blocks x 256 thr. Prologue (R6-verified): per-block 27x32 offsets GEMM
// -> offv (stride 36). Main (R3-verified, 69.9us): full o=256, glds16 sA
// (32KB, 32 units), single-buffer 2-barrier chunk loop, gathers+lerp -> sB,
// 16 MFMA/wave/chunk, setprio, unroll 4. Epilogue BN+relu+residual.
__global__ __launch_bounds__(256) void fused_kernel(
    const float* __restrict__ x, const u16* __restrict__ XT,
    const u16* __restrict__ WO, const float* __restrict__ b_off,
    const u16* __restrict__ WQ, const float* __restrict__ AB,
    float* __restrict__ out)
{
    __shared__ __align__(16) unsigned char smem[41472];
    u16*   sA   = (u16*)smem;                                // 32 KB
    u16*   sB   = (u16*)(smem + 32768);                      //  4 KB
    float* offv = (float*)(smem + 36864);                    // [32][36] 4.6 KB
    float (*red)[2][32][17] = (float (*)[2][32][17])smem;    // prologue alias

    const int tid  = threadIdx.x;
    const int wave = tid >> 6;
    const int lane = tid & 63;
    const int quad = lane >> 4;
    const int l15  = lane & 15;

    // 576 = 8*72 bijective XCD swizzle
    const int bid = blockIdx.x;
    const int swz = (bid & 7) * 72 + (bid >> 3);
    const int n0  = swz * 32;
    const int b   = n0 / HW_;
    const int p0  = n0 - b * HW_;
    const int h   = p0 / W_;                 // 32-px tile fits one row
    const int w0  = p0 % W_;

    // ---------- prologue: offsets GEMM for this block's 32 px ----------
    {
        float4v oa[2][2];
#pragma unroll
        for (int ph = 0; ph < 2; ph++)
#pragma unroll
            for (int hh = 0; hh < 2; hh++)
                oa[ph][hh] = float4v{0.f, 0.f, 0.f, 0.f};

        int basec0 = 0, basec1 = 0; bool vld0 = true, vld1 = true;
        auto oset = [&](int tap) {
            int py = h + tap / 3 - 1;
            bool vy = (unsigned)py < (unsigned)H_;
            int pyc = min(max(py, 0), H_ - 1);
            int rowb = (b * H_ + pyc) * W_;
            {
                int pxl = w0 + l15 + tap % 3 - 1;
                vld0 = vy && ((unsigned)pxl < (unsigned)W_);
                basec0 = (rowb + min(max(pxl, 0), W_ - 1)) * C_ + quad * 8;
            }
            {
                int pxl = w0 + 16 + l15 + tap % 3 - 1;
                vld1 = vy && ((unsigned)pxl < (unsigned)W_);
                basec1 = (rowb + min(max(pxl, 0), W_ - 1)) * C_ + quad * 8;
            }
        };
        auto bld0 = [&](int c32) -> ushort8 {
            ushort8 v = *(const ushort8*)(XT + basec0 + (c32 & 7) * 32);
#pragma unroll
            for (int j = 0; j < 8; j++) v[j] = vld0 ? v[j] : (u16)0;
            return v;
        };
        auto bld1 = [&](int c32) -> ushort8 {
            ushort8 v = *(const ushort8*)(XT + basec1 + (c32 & 7) * 32);
#pragma unroll
            for (int j = 0; j < 8; j++) v[j] = vld1 ? v[j] : (u16)0;
            return v;
        };
        const int i0 = wave * 18, i1 = i0 + 18;
        int curtap = i0 >> 3;
        oset(curtap);
        ushort8 b0 = bld0(i0), b1 = bld1(i0);
        short8v wa = *(const short8v*)(WO + i0 * 1024 + l15 * 32 + quad * 8);
        short8v wb = *(const short8v*)(WO + i0 * 1024 + l15 * 32 + quad * 8 + 512);
        for (int i = i0; i < i1; ++i) {
            ushort8 c0v = b0, c1v = b1;
            short8v wac = wa, wbc = wb;
            int nx = i + 1;
            if (nx < i1) {
                int t = nx >> 3;
                if (t != curtap) { oset(t); curtap = t; }
                b0 = bld0(nx); b1 = bld1(nx);
                wa = *(const short8v*)(WO + nx * 1024 + l15 * 32 + quad * 8);
                wb = *(const short8v*)(WO + nx * 1024 + l15 * 32 + quad * 8 + 512);
            }
            union { ushort8 u; short8v s; } u0, u1; u0.u = c0v; u1.u = c1v;
            oa[0][0] = __builtin_amdgcn_mfma_f32_16x16x32_bf16(wac, u0.s, oa[0][0], 0, 0, 0);
            oa[0][1] = __builtin_amdgcn_mfma_f32_16x16x32_bf16(wbc, u0.s, oa[0][1], 0, 0, 0);
            oa[1][0] = __builtin_amdgcn_mfma_f32_16x16x32_bf16(wac, u1.s, oa[1][0], 0, 0, 0);
            oa[1][1] = __builtin_amdgcn_mfma_f32_16x16x32_bf16(wbc, u1.s, oa[1][1], 0, 0, 0);
        }
#pragma unroll
        for (int r = 0; r < 4; ++r) {
            red[wave][0][quad * 4 + r][l15]      = oa[0][0][r];
            red[wave][0][16 + quad * 4 + r][l15] = oa[0][1][r];
            red[wave][1][quad * 4 + r][l15]      = oa[1][0][r];
            red[wave][1][16 + quad * 4 + r][l15] = oa[1][1][r];
        }
    }
    __syncthreads();
    for (int u = tid; u < 1024; u += 256) {
        int px = u & 31, o = u >> 5;
        if (o < KO_) {
            int ph = px >> 4, pp = px & 15;
            float v = red[0][ph][o][pp] + red[1][ph][o][pp]
                    + red[2][ph][o][pp] + red[3][ph][o][pp] + b_off[o];
            offv[px * 36 + o] = (o < 18) ? v : 1.f / (1.f + expf(-v));
        }
    }
    __syncthreads();     // offv ready; red region free for sA

    // ---------- main loop (R3 structure, 69.9us measured) ----------
    float4v acc[4][2];
#pragma unroll
    for (int i = 0; i < 4; i++)
#pragma unroll
        for (int jj = 0; jj < 2; jj++)
            acc[i][jj] = float4v{0.f, 0.f, 0.f, 0.f};

    const int le8 = lane * 8;
    const int wo  = wave * 64;

    const int ppx = tid >> 3;
    const int pj  = tid & 7;
    const int sboff = (pj >> 2) * 1024 + ppx * 32 + (pj & 3) * 8;

    float fc0, fc1, fc2, fc3, fn0, fn1, fn2, fn3;
    int a00, a01, a10, a11;

    auto tap_setup = [&](int tap) {
        float dy = offv[ppx * 36 + 2 * tap];
        float dx = offv[ppx * 36 + 2 * tap + 1];
        float m  = offv[ppx * 36 + 18 + tap];
        float py  = (float)(h + tap / 3 - 1) + dy;
        float pxx = (float)(w0 + ppx + tap % 3 - 1) + dx;
        float y0f = floorf(py), x0f = floorf(pxx);
        float ly = py - y0f, lx = pxx - x0f;
        int y0 = (int)y0f, x0i = (int)x0f;
        int y1 = y0 + 1, x1 = x0i + 1;
        bool vy0 = (unsigned)y0 < (unsigned)H_;
        bool vy1 = (unsigned)y1 < (unsigned)H_;
        bool vx0 = (unsigned)x0i < (unsigned)W_;
        bool vx1 = (unsigned)x1 < (unsigned)W_;
        fn0 = (vy0 && vx0) ? (1.f - ly) * (1.f - lx) * m : 0.f;
        fn1 = (vy0 && vx1) ? (1.f - ly) * lx * m : 0.f;
        fn2 = (vy1 && vx0) ? ly * (1.f - lx) * m : 0.f;
        fn3 = (vy1 && vx1) ? ly * lx * m : 0.f;
        int y0c = min(max(y0, 0), H_ - 1), y1c = min(max(y1, 0), H_ - 1);
        int x0c = min(max(x0i, 0), W_ - 1), x1c = min(max(x1, 0), W_ - 1);
        a00 = ((b * H_ + y0c) * W_ + x0c) * C_;
        a01 = ((b * H_ + y0c) * W_ + x1c) * C_;
        a10 = ((b * H_ + y1c) * W_ + x0c) * C_;
        a11 = ((b * H_ + y1c) * W_ + x1c) * C_;
    };
    auto stageA = [&](int tap, int q) {
#pragma unroll
        for (int i = 0; i < 8; ++i) {
            int unit = i * 4 + wave;                 // 0..31, wave-uniform
            int cc = unit >> 4;
            glds16(WQ + (size_t)(tap * 8 + q * 2 + cc) * 8192
                      + (unit & 15) * 512 + le8,
                   &sA[unit * 512]);
        }
    };

    // ---- prologue: tap 0, chunk 0 gathers + A-stage ----
    tap_setup(0);
    fc0 = fn0; fc1 = fn1; fc2 = fn2; fc3 = fn3;
    ushort8 gc00 = *(const ushort8*)(XT + a00 + pj * 8);
    ushort8 gc01 = *(const ushort8*)(XT + a01 + pj * 8);
    ushort8 gc10 = *(const ushort8*)(XT + a10 + pj * 8);
    ushort8 gc11 = *(const ushort8*)(XT + a11 + pj * 8);
    stageA(0, 0);
    ushort8 gn00{}, gn01{}, gn10{}, gn11{};

#pragma unroll 4
    for (int ch = 0; ch < 36; ++ch) {
        // ---- P1: lerp current gathers -> sB ----
        {
            float v[8];
#pragma unroll
            for (int t = 0; t < 8; t++)
                v[t] = fc0 * b2f(gc00[t]) + fc1 * b2f(gc01[t])
                     + fc2 * b2f(gc10[t]) + fc3 * b2f(gc11[t]);
            uint4 sv;
            sv.x = pack2(v[0], v[1]);
            sv.y = pack2(v[2], v[3]);
            sv.z = pack2(v[4], v[5]);
            sv.w = pack2(v[6], v[7]);
            *(uint4*)&sB[sboff] = sv;
        }
        asm volatile("s_waitcnt vmcnt(0) lgkmcnt(0)" ::: "memory");
        __builtin_amdgcn_s_barrier();            // sA + sB for ch ready

        // ---- P2: fragment reads ----
        short8v af[2][4], bfr[2][2];
#pragma unroll
        for (int cc = 0; cc < 2; ++cc) {
#pragma unroll
            for (int mt = 0; mt < 4; ++mt)
                af[cc][mt] = *(const short8v*)
                    &sA[cc * 8192 + (wo + mt * 16 + l15) * 32 + quad * 8];
#pragma unroll
            for (int nt = 0; nt < 2; ++nt)
                bfr[cc][nt] = *(const short8v*)
                    &sB[cc * 1024 + (nt * 16 + l15) * 32 + quad * 8];
        }
        asm volatile("s_waitcnt lgkmcnt(0)" ::: "memory");
        __builtin_amdgcn_s_barrier();            // reads done; sA/sB free

        // ---- P3: prefetch chunk ch+1 (gathers + A-stage), then MFMA ----
        if (ch < 35) {
            const int chn = ch + 1, tapn = chn >> 2, qn = chn & 3;
            if (qn == 0) tap_setup(tapn);
            const int cb = qn * 64 + pj * 8;
            gn00 = *(const ushort8*)(XT + a00 + cb);
            gn01 = *(const ushort8*)(XT + a01 + cb);
            gn10 = *(const ushort8*)(XT + a10 + cb);
            gn11 = *(const ushort8*)(XT + a11 + cb);
            stageA(tapn, qn);
        }
        __builtin_amdgcn_s_setprio(1);
#pragma unroll
        for (int cc = 0; cc < 2; ++cc)
#pragma unroll
            for (int mt = 0; mt < 4; ++mt)
#pragma unroll
                for (int nt = 0; nt < 2; ++nt)
                    acc[mt][nt] = __builtin_amdgcn_mfma_f32_16x16x32_bf16(
                        af[cc][mt], bfr[cc][nt], acc[mt][nt], 0, 0, 0);
        __builtin_amdgcn_s_setprio(0);
        gc00 = gn00; gc01 = gn01; gc10 = gn10; gc11 = gn11;
        fc0 = fn0; fc1 = fn1; fc2 = fn2; fc3 = fn3;
    }

    // epilogue: BN fold + relu + residual
    const float* Ao = AB;
    const float* Bo = AB + 256;
#pragma unroll
    for (int mt = 0; mt < 4; mt++) {
#pragma unroll
        for (int nt = 0; nt < 2; nt++) {
            int pix = p0 + nt * 16 + l15;
#pragma unroll
            for (int r = 0; r < 4; r++) {
                int o = wo + mt * 16 + quad * 4 + r;
                float v = acc[mt][nt][r] * Ao[o] + Bo[o];
                v = fmaxf(v, 0.f);
                int gi = (b * C_ + o) * HW_ + pix;
                out[gi] = x[gi] + v;
            }
        }
    }
}

extern "C" void kernel_launch(void* const* d_in, const int* in_sizes, int n_in,
                              void* d_out, int out_size, void* d_ws, size_t ws_size,
                              hipStream_t stream)
{
    (void)in_sizes; (void)n_in; (void)out_size; (void)ws_size;
    const float* x      = (const float*)d_in[0];
    const float* w_off  = (const float*)d_in[1];
    const float* b_off  = (const float*)d_in[2];
    const float* w_conv = (const float*)d_in[3];
    const float* b_conv = (const float*)d_in[4];
    const float* gamma  = (const float*)d_in[5];
    const float* beta   = (const float*)d_in[6];
    const float* rmean  = (const float*)d_in[7];
    const float* rvar   = (const float*)d_in[8];
    float* out = (float*)d_out;

    float* ws = (float*)d_ws;
    float* AB = ws;                            // 512 floats
    u16* WQ = (u16*)(AB + 512);                // 589824 u16
    u16* WO = WQ + 589824;                     // 73728 u16
    u16* XT = WO + 73728;                      // 4718592 u16

    prep_kernel<<<865, 256, 0, stream>>>(x, w_conv, w_off, b_conv, gamma, beta,
                                         rmean, rvar, AB, WQ, WO, XT);
    fused_kernel<<<576, 256, 0, stream>>>(x, XT, WO, b_off, WQ, AB, out);
}